// Round 2
// baseline (740.572 us; speedup 1.0000x reference)
//
#include <hip/hip_runtime.h>

typedef unsigned short u16;
typedef unsigned int u32;
typedef __attribute__((ext_vector_type(8))) short bf16x8;
typedef __attribute__((ext_vector_type(4))) float f32x4;

__device__ __forceinline__ u16 f2bf(float f) {
  u32 u = __float_as_uint(f);
  u32 r = (u + 0x7FFFu + ((u >> 16) & 1u)) >> 16;  // RTNE
  return (u16)r;
}

__device__ __forceinline__ void gl_lds16(const u16* g, u16* l) {
  __builtin_amdgcn_global_load_lds(
      (const __attribute__((address_space(1))) u32*)g,
      (__attribute__((address_space(3))) u32*)l, 16, 0, 0);
}

// ---------------- prep: U fp32 -> bf16 ----------------
__global__ __launch_bounds__(256) void cvt_bf16(const float* __restrict__ src,
                                                u16* __restrict__ dst, int n4) {
  int g = blockIdx.x * 256 + threadIdx.x;
  if (g < n4) {
    float4 v = ((const float4*)src)[g];
    ushort4 o;
    o.x = f2bf(v.x); o.y = f2bf(v.y); o.z = f2bf(v.z); o.w = f2bf(v.w);
    ((ushort4*)dst)[g] = o;
  }
}

// ---------------- prep: x fp32 -> Xb bf16 [b][l][d] and XT bf16 [b][d][l] ----------------
__global__ __launch_bounds__(256) void prep_x(const float* __restrict__ x,
                                              u16* __restrict__ Xb,
                                              u16* __restrict__ XT) {
  __shared__ u16 t[32][33];
  const int b = blockIdx.z;
  const int l0 = blockIdx.y * 32;
  const int d0 = blockIdx.x * 32;
  const int j = threadIdx.x & 31;
  const int t5 = threadIdx.x >> 5;
#pragma unroll
  for (int r = 0; r < 4; r++) {
    int i = r * 8 + t5;
    float v = x[((size_t)b * 2048 + l0 + i) * 512 + d0 + j];
    u16 h = f2bf(v);
    t[i][j] = h;
    Xb[((size_t)b * 2048 + l0 + i) * 512 + d0 + j] = h;
  }
  __syncthreads();
#pragma unroll
  for (int r = 0; r < 4; r++) {
    int i = r * 8 + t5;
    XT[((size_t)b * 512 + d0 + i) * 2048 + l0 + j] = t[j][i];
  }
}

__global__ __launch_bounds__(256) void zero_f32(float* __restrict__ p, int n) {
  int g = blockIdx.x * 256 + threadIdx.x;
  if (g < n) p[g] = 0.f;
}

// ---------------- GEMM: C = A[M][Kstride-major] @ B[N][Kstride-major]^T ----------------
// 128x128 tile, m97 structure. blockIdx.z = K-split index (A,B advance by z*Kloop in k).
// EPI=0: out = bf16(exp(acc)) -> u16* stride N; fused rowsum atomicAdd into z[row]
// EPI=1: out = acc (f32 partial) -> (float*)Cout + blockIdx.z*splitStride
// EPI=2: out = acc / z[row] -> float* stride N (direct, no split)
template <int EPI>
__global__ __launch_bounds__(256)
void gemm_bt(const u16* __restrict__ A, const u16* __restrict__ B,
             void* __restrict__ Cout, float* __restrict__ z,
             int Kstride, int Kloop, int N, size_t splitStride) {
  __shared__ u16 lA[128 * 32];
  __shared__ u16 lB[128 * 32];
  __shared__ float rz_lds[128];
  const int tid = threadIdx.x;
  const int lane = tid & 63;
  const int wv = tid >> 6;            // wave 0..3
  const int m0 = blockIdx.y * 128;
  const int n0 = blockIdx.x * 128;
  const int ks = blockIdx.z;
  if (EPI == 2 && tid < 128) rz_lds[tid] = 1.f / z[m0 + tid];
  const int wy = wv >> 1, wx = wv & 1;  // 2x2 wave grid, 64x64 per wave
  const int sr = lane >> 2;             // staging row in 16-row chunk
  const int sc = (lane & 3) * 8;        // staging k offset (elems)
  const int fr = lane & 15;             // fragment row/col
  const int fo = (lane >> 4) * 8;       // fragment k offset

  f32x4 acc[4][4] = {};
  const u16* Ab = A + (size_t)(m0 + wv * 32 + sr) * Kstride + sc + (size_t)ks * Kloop;
  const u16* Bb = B + (size_t)(n0 + wv * 32 + sr) * Kstride + sc + (size_t)ks * Kloop;
  const size_t rowskip = (size_t)16 * Kstride;

  for (int k0 = 0; k0 < Kloop; k0 += 32) {
    gl_lds16(Ab + k0,           &lA[(wv * 2 + 0) * 512]);
    gl_lds16(Ab + k0 + rowskip, &lA[(wv * 2 + 1) * 512]);
    gl_lds16(Bb + k0,           &lB[(wv * 2 + 0) * 512]);
    gl_lds16(Bb + k0 + rowskip, &lB[(wv * 2 + 1) * 512]);
    __syncthreads();
    bf16x8 af[4], bfr[4];
#pragma unroll
    for (int t = 0; t < 4; t++) {
      af[t]  = *(const bf16x8*)&lA[(wy * 64 + t * 16 + fr) * 32 + fo];
      bfr[t] = *(const bf16x8*)&lB[(wx * 64 + t * 16 + fr) * 32 + fo];
    }
#pragma unroll
    for (int yb = 0; yb < 4; yb++)
#pragma unroll
      for (int xb = 0; xb < 4; xb++)
        acc[yb][xb] = __builtin_amdgcn_mfma_f32_16x16x32_bf16(
            af[yb], bfr[xb], acc[yb][xb], 0, 0, 0);
    __syncthreads();
  }

  float* fout = (EPI == 1) ? ((float*)Cout + (size_t)ks * splitStride) : (float*)Cout;

#pragma unroll
  for (int yb = 0; yb < 4; yb++) {
    const int rl = wy * 64 + yb * 16 + (lane >> 4) * 4;  // local row (0..127)
    float rs[4] = {0.f, 0.f, 0.f, 0.f};
#pragma unroll
    for (int xb = 0; xb < 4; xb++) {
      const int col = n0 + wx * 64 + xb * 16 + fr;
#pragma unroll
      for (int r = 0; r < 4; r++) {
        if (EPI == 0) {
          float e = __expf(acc[yb][xb][r]);
          ((u16*)Cout)[(size_t)(m0 + rl + r) * N + col] = f2bf(e);
          rs[r] += e;
        } else if (EPI == 1) {
          fout[(size_t)(m0 + rl + r) * N + col] = acc[yb][xb][r];
        } else {
          fout[(size_t)(m0 + rl + r) * N + col] = acc[yb][xb][r] * rz_lds[rl + r];
        }
      }
    }
    if (EPI == 0) {
#pragma unroll
      for (int m = 1; m < 16; m <<= 1)
#pragma unroll
        for (int r = 0; r < 4; r++) rs[r] += __shfl_xor(rs[r], m);
      if ((lane & 15) == 0) {
#pragma unroll
        for (int r = 0; r < 4; r++) atomicAdd(&z[m0 + rl + r], rs[r]);
      }
    }
  }
}

// ---------------- combine 4 split-K partials, scale by 1/z ----------------
__global__ __launch_bounds__(256) void combine4(const float* __restrict__ pbuf,
                                                const float* __restrict__ z,
                                                float* __restrict__ out) {
  int g = blockIdx.x * 256 + threadIdx.x;  // float4 index, [0, 8192*512/4)
  int row = g >> 7;                        // 128 float4 per row
  float rz = 1.f / z[row];
  const float4* p = (const float4*)pbuf;
  float4 a = p[g];
  float4 b = p[g + 1048576];
  float4 c = p[g + 2097152];
  float4 d = p[g + 3145728];
  float4 o;
  o.x = (a.x + b.x + c.x + d.x) * rz;
  o.y = (a.y + b.y + c.y + d.y) * rz;
  o.z = (a.z + b.z + c.z + d.z) * rz;
  o.w = (a.w + b.w + c.w + d.w) * rz;
  ((float4*)out)[g] = o;
}

// B=8, L=2048, D=512, Y=8192
extern "C" void kernel_launch(void* const* d_in, const int* in_sizes, int n_in,
                              void* d_out, int out_size, void* d_ws, size_t ws_size,
                              hipStream_t stream) {
  const float* x = (const float*)d_in[0];   // [8][2048][512]
  const float* U = (const float*)d_in[1];   // [8192][512]
  if (n_in >= 2 && in_sizes[0] == 8192 * 512) {
    x = (const float*)d_in[1];
    U = (const float*)d_in[0];
  }
  float* out = (float*)d_out;               // [8][8192][512]
  char* ws = (char*)d_ws;

  // ws layout (bytes)
  u16* Ub   = (u16*)ws;                                   // 8 MiB
  u16* Xb   = (u16*)(ws + 8388608);                       // 16 MiB
  u16* XT   = (u16*)(ws + 25165824);                      // 16 MiB
  u16* P    = (u16*)(ws + 41943040);                      // 32 MiB
  float* z  = (float*)(ws + 75497472);                    // 8*8192*4 = 256 KiB
  float* pbuf = (float*)(ws + 75759616);                  // 4*16 MiB = 64 MiB
  const size_t need_split = 75759616ull + 67108864ull;    // ~136.3 MiB
  const bool use_split = ws_size >= need_split;

  cvt_bf16<<<4096, 256, 0, stream>>>(U, Ub, (8192 * 512) / 4);
  prep_x<<<dim3(16, 64, 8), 256, 0, stream>>>(x, Xb, XT);
  zero_f32<<<256, 256, 0, stream>>>(z, 8 * 8192);

  for (int b = 0; b < 8; b++) {
    float* zb = z + b * 8192;
    // P = exp(U @ x_b^T), fused rowsum -> zb: M=8192, N=2048, K=512
    gemm_bt<0><<<dim3(16, 64, 1), 256, 0, stream>>>(
        Ub, Xb + (size_t)b * 2048 * 512, P, zb, 512, 512, 2048, 0);
    if (use_split) {
      // pbuf[s] = P[:, s*512:(s+1)*512] @ XT[:, s*512:(s+1)*512]^T
      gemm_bt<1><<<dim3(4, 64, 4), 256, 0, stream>>>(
          P, XT + (size_t)b * 512 * 2048, pbuf, nullptr, 2048, 512, 512,
          (size_t)8192 * 512);
      combine4<<<4096, 256, 0, stream>>>(pbuf, zb, out + (size_t)b * 8192 * 512);
    } else {
      gemm_bt<2><<<dim3(4, 64, 1), 256, 0, stream>>>(
          P, XT + (size_t)b * 512 * 2048, out + (size_t)b * 8192 * 512, zb,
          2048, 2048, 512, 0);
    }
  }
}

// Round 3
// 564.557 us; speedup vs baseline: 1.3118x; 1.3118x over previous
//
#include <hip/hip_runtime.h>

typedef unsigned short u16;
typedef unsigned int u32;
typedef __attribute__((ext_vector_type(8))) short bf16x8;
typedef __attribute__((ext_vector_type(4))) float f32x4;

__device__ __forceinline__ u16 f2bf(float f) {
  u32 u = __float_as_uint(f);
  u32 r = (u + 0x7FFFu + ((u >> 16) & 1u)) >> 16;  // RTNE
  return (u16)r;
}

__device__ __forceinline__ void gl_lds16(const u16* g, u16* l) {
  __builtin_amdgcn_global_load_lds(
      (const __attribute__((address_space(1))) u32*)g,
      (__attribute__((address_space(3))) u32*)l, 16, 0, 0);
}

// ---------------- prep: U fp32 -> bf16 ----------------
__global__ __launch_bounds__(256) void cvt_bf16(const float* __restrict__ src,
                                                u16* __restrict__ dst, int n4) {
  int g = blockIdx.x * 256 + threadIdx.x;
  if (g < n4) {
    float4 v = ((const float4*)src)[g];
    ushort4 o;
    o.x = f2bf(v.x); o.y = f2bf(v.y); o.z = f2bf(v.z); o.w = f2bf(v.w);
    ((ushort4*)dst)[g] = o;
  }
}

// ---------------- prep: x fp32 -> Xb bf16 [b][l][d] and XT bf16 [b][d][l] ----------------
__global__ __launch_bounds__(256) void prep_x(const float* __restrict__ x,
                                              u16* __restrict__ Xb,
                                              u16* __restrict__ XT) {
  __shared__ u16 t[32][33];
  const int b = blockIdx.z;
  const int l0 = blockIdx.y * 32;
  const int d0 = blockIdx.x * 32;
  const int j = threadIdx.x & 31;
  const int t5 = threadIdx.x >> 5;
#pragma unroll
  for (int r = 0; r < 4; r++) {
    int i = r * 8 + t5;
    float v = x[((size_t)b * 2048 + l0 + i) * 512 + d0 + j];
    u16 h = f2bf(v);
    t[i][j] = h;
    Xb[((size_t)b * 2048 + l0 + i) * 512 + d0 + j] = h;
  }
  __syncthreads();
#pragma unroll
  for (int r = 0; r < 4; r++) {
    int i = r * 8 + t5;
    XT[((size_t)b * 512 + d0 + i) * 2048 + l0 + j] = t[j][i];
  }
}

__global__ __launch_bounds__(256) void zero_f32(float* __restrict__ p, int n) {
  int g = blockIdx.x * 256 + threadIdx.x;
  if (g < n) p[g] = 0.f;
}

// ---------------- batched GEMM: C[b] = A[b][M][K] @ B[b][N][K]^T ----------------
// 128x128 tile, m97 structure. Grid (gx, gy, nb); XCD-bijective swizzle over the
// flattened grid (nwg % 8 == 0 in all our launches).
// EPI=0: out = bf16(exp(acc)) -> u16* stride N; fused rowsum atomicAdd into z[bz*8192+row]
// EPI=2: out = acc / z[bz*8192+row] -> float* stride N
template <int EPI>
__global__ __launch_bounds__(256)
void gemm_bt(const u16* __restrict__ A, const u16* __restrict__ B,
             void* __restrict__ Cout, float* __restrict__ z,
             int Kstride, int N,
             size_t Ab_str, size_t Bb_str, size_t Cb_str, int gx, int gy) {
  __shared__ u16 lA[128 * 32];
  __shared__ u16 lB[128 * 32];
  __shared__ float rz_lds[128];

  // flatten + XCD swizzle (bijective: nwg % 8 == 0)
  const int nwg = gx * gy * gridDim.z;
  const int orig = blockIdx.x + gx * (blockIdx.y + gy * blockIdx.z);
  const int cpx = nwg >> 3;
  const int nid = (orig & 7) * cpx + (orig >> 3);
  const int bxi = nid % gx;
  const int byi = (nid / gx) % gy;
  const int bzi = nid / (gx * gy);

  const int tid = threadIdx.x;
  const int lane = tid & 63;
  const int wv = tid >> 6;            // wave 0..3
  const int m0 = byi * 128;
  const int n0 = bxi * 128;
  const u16* Ab0 = A + (size_t)bzi * Ab_str;
  const u16* Bb0 = B + (size_t)bzi * Bb_str;
  float* zb = z + (size_t)bzi * 8192;
  if (EPI == 2 && tid < 128) rz_lds[tid] = 1.f / zb[m0 + tid];

  const int wy = wv >> 1, wx = wv & 1;  // 2x2 wave grid, 64x64 per wave
  const int sr = lane >> 2;             // staging row in 16-row chunk
  const int sc = (lane & 3) * 8;        // staging k offset (elems)
  const int fr = lane & 15;             // fragment row/col
  const int fo = (lane >> 4) * 8;       // fragment k offset

  f32x4 acc[4][4] = {};
  const u16* Ab = Ab0 + (size_t)(m0 + wv * 32 + sr) * Kstride + sc;
  const u16* Bb = Bb0 + (size_t)(n0 + wv * 32 + sr) * Kstride + sc;
  const size_t rowskip = (size_t)16 * Kstride;

  for (int k0 = 0; k0 < Kstride; k0 += 32) {
    gl_lds16(Ab + k0,           &lA[(wv * 2 + 0) * 512]);
    gl_lds16(Ab + k0 + rowskip, &lA[(wv * 2 + 1) * 512]);
    gl_lds16(Bb + k0,           &lB[(wv * 2 + 0) * 512]);
    gl_lds16(Bb + k0 + rowskip, &lB[(wv * 2 + 1) * 512]);
    __syncthreads();
    bf16x8 af[4], bfr[4];
#pragma unroll
    for (int t = 0; t < 4; t++) {
      af[t]  = *(const bf16x8*)&lA[(wy * 64 + t * 16 + fr) * 32 + fo];
      bfr[t] = *(const bf16x8*)&lB[(wx * 64 + t * 16 + fr) * 32 + fo];
    }
#pragma unroll
    for (int yb = 0; yb < 4; yb++)
#pragma unroll
      for (int xb = 0; xb < 4; xb++)
        acc[yb][xb] = __builtin_amdgcn_mfma_f32_16x16x32_bf16(
            af[yb], bfr[xb], acc[yb][xb], 0, 0, 0);
    __syncthreads();
  }

#pragma unroll
  for (int yb = 0; yb < 4; yb++) {
    const int rl = wy * 64 + yb * 16 + (lane >> 4) * 4;  // local row (0..127)
    float rs[4] = {0.f, 0.f, 0.f, 0.f};
#pragma unroll
    for (int xb = 0; xb < 4; xb++) {
      const int col = n0 + wx * 64 + xb * 16 + fr;
#pragma unroll
      for (int r = 0; r < 4; r++) {
        if (EPI == 0) {
          float e = __expf(acc[yb][xb][r]);
          ((u16*)Cout)[(size_t)bzi * Cb_str + (size_t)(m0 + rl + r) * N + col] = f2bf(e);
          rs[r] += e;
        } else {
          ((float*)Cout)[(size_t)bzi * Cb_str + (size_t)(m0 + rl + r) * N + col] =
              acc[yb][xb][r] * rz_lds[rl + r];
        }
      }
    }
    if (EPI == 0) {
#pragma unroll
      for (int m = 1; m < 16; m <<= 1)
#pragma unroll
        for (int r = 0; r < 4; r++) rs[r] += __shfl_xor(rs[r], m);
      if ((lane & 15) == 0) {
#pragma unroll
        for (int r = 0; r < 4; r++) atomicAdd(&zb[m0 + rl + r], rs[r]);
      }
    }
  }
}

// B=8, L=2048, D=512, Y=8192
extern "C" void kernel_launch(void* const* d_in, const int* in_sizes, int n_in,
                              void* d_out, int out_size, void* d_ws, size_t ws_size,
                              hipStream_t stream) {
  const float* x = (const float*)d_in[0];   // [8][2048][512]
  const float* U = (const float*)d_in[1];   // [8192][512]
  if (n_in >= 2 && in_sizes[0] == 8192 * 512) {
    x = (const float*)d_in[1];
    U = (const float*)d_in[0];
  }
  float* out = (float*)d_out;               // [8][8192][512]
  char* ws = (char*)d_ws;

  // ws layout (bytes)
  u16* Ub = (u16*)ws;                       // 8 MiB
  u16* Xb = (u16*)(ws + 8388608);           // 16 MiB
  u16* XT = (u16*)(ws + 25165824);          // 16 MiB
  u16* P  = (u16*)(ws + 41943040);          // all-batch: 256 MiB; per-batch: 32 MiB
  const size_t need_all = 41943040ull + 268435456ull + 262144ull;  // ~296.5 MiB

  cvt_bf16<<<4096, 256, 0, stream>>>(U, Ub, (8192 * 512) / 4);
  prep_x<<<dim3(16, 64, 8), 256, 0, stream>>>(x, Xb, XT);

  if (ws_size >= need_all) {
    float* z = (float*)(ws + 41943040 + 268435456);
    zero_f32<<<256, 256, 0, stream>>>(z, 8 * 8192);
    // P[b] = exp(U @ x_b^T), fused rowsum -> z[b]: M=8192, N=2048, K=512
    gemm_bt<0><<<dim3(16, 64, 8), 256, 0, stream>>>(
        Ub, Xb, P, z, 512, 2048,
        /*Ab_str=*/0, /*Bb_str=*/(size_t)2048 * 512, /*Cb_str=*/(size_t)8192 * 2048,
        16, 64);
    // out[b] = (P[b] @ XT_b^T) / z[b]: M=8192, N=512, K=2048
    gemm_bt<2><<<dim3(4, 64, 8), 256, 0, stream>>>(
        P, XT, out, z, 2048, 512,
        /*Ab_str=*/(size_t)8192 * 2048, /*Bb_str=*/(size_t)512 * 2048,
        /*Cb_str=*/(size_t)8192 * 512, 4, 64);
  } else {
    // fallback: per-batch P (32 MiB)
    float* z = (float*)(ws + 41943040 + 33554432);
    zero_f32<<<256, 256, 0, stream>>>(z, 8 * 8192);
    for (int b = 0; b < 8; b++) {
      gemm_bt<0><<<dim3(16, 64, 1), 256, 0, stream>>>(
          Ub, Xb + (size_t)b * 2048 * 512, P, z + b * 8192, 512, 2048,
          0, 0, 0, 16, 64);
      gemm_bt<2><<<dim3(4, 64, 1), 256, 0, stream>>>(
          P, XT + (size_t)b * 512 * 2048, out + (size_t)b * 8192 * 512,
          z + b * 8192, 2048, 512, 0, 0, 0, 4, 64);
    }
  }
}

// Round 4
// 522.982 us; speedup vs baseline: 1.4161x; 1.0795x over previous
//
#include <hip/hip_runtime.h>

typedef unsigned short u16;
typedef unsigned int u32;
typedef __attribute__((ext_vector_type(8))) short bf16x8;
typedef __attribute__((ext_vector_type(4))) float f32x4;

__device__ __forceinline__ u16 f2bf(float f) {
  u32 u = __float_as_uint(f);
  u32 r = (u + 0x7FFFu + ((u >> 16) & 1u)) >> 16;  // RTNE
  return (u16)r;
}

__device__ __forceinline__ void gl_lds16(const u16* g, u16* l) {
  __builtin_amdgcn_global_load_lds(
      (const __attribute__((address_space(1))) u32*)g,
      (__attribute__((address_space(3))) u32*)l, 16, 0, 0);
}

// ---------------- prep: U fp32 -> bf16 ----------------
__global__ __launch_bounds__(256) void cvt_bf16(const float* __restrict__ src,
                                                u16* __restrict__ dst, int n4) {
  int g = blockIdx.x * 256 + threadIdx.x;
  if (g < n4) {
    float4 v = ((const float4*)src)[g];
    ushort4 o;
    o.x = f2bf(v.x); o.y = f2bf(v.y); o.z = f2bf(v.z); o.w = f2bf(v.w);
    ((ushort4*)dst)[g] = o;
  }
}

// ---------------- prep: x fp32 -> Xb bf16 [b][l][d] and XT bf16 [b][d][l] ----------------
__global__ __launch_bounds__(256) void prep_x(const float* __restrict__ x,
                                              u16* __restrict__ Xb,
                                              u16* __restrict__ XT) {
  __shared__ u16 t[32][33];
  const int b = blockIdx.z;
  const int l0 = blockIdx.y * 32;
  const int d0 = blockIdx.x * 32;
  const int j = threadIdx.x & 31;
  const int t5 = threadIdx.x >> 5;
#pragma unroll
  for (int r = 0; r < 4; r++) {
    int i = r * 8 + t5;
    float v = x[((size_t)b * 2048 + l0 + i) * 512 + d0 + j];
    u16 h = f2bf(v);
    t[i][j] = h;
    Xb[((size_t)b * 2048 + l0 + i) * 512 + d0 + j] = h;
  }
  __syncthreads();
#pragma unroll
  for (int r = 0; r < 4; r++) {
    int i = r * 8 + t5;
    XT[((size_t)b * 512 + d0 + i) * 2048 + l0 + j] = t[j][i];
  }
}

__global__ __launch_bounds__(256) void zero_f32(float* __restrict__ p, int n) {
  int g = blockIdx.x * 256 + threadIdx.x;
  if (g < n) p[g] = 0.f;
}

// ---------------- 256x256-tile batched GEMM: C[b] = A[b] @ B[b]^T ----------------
// BK=64, 8 waves (2M x 4N), double-buffered LDS with st-style XOR swizzle
// (byte ^= (row&7)<<4), distance-1 prefetch, one barrier per K-tile.
// EPI=0: out = bf16(exp(acc)) -> u16* stride N; fused rowsum atomicAdd into z
// EPI=2: out = acc / z[row]   -> float* stride N
template <int EPI>
__global__ __launch_bounds__(512, 2)
void gemm256(const u16* __restrict__ A, const u16* __restrict__ B,
             void* __restrict__ Cout, float* __restrict__ z,
             int Kstride, int nt, int N,
             size_t Ab_str, size_t Bb_str, size_t Cb_str, int gx, int gy) {
  __shared__ u16 lA[2][16384];   // [buf][256 rows][64 k] swizzled, 32 KiB each
  __shared__ u16 lB[2][16384];
  __shared__ float rz_lds[256];

  // flatten + XCD-bijective swizzle (nwg % 8 == 0 in all launches)
  const int nwg = gx * gy * gridDim.z;
  const int orig = blockIdx.x + gx * (blockIdx.y + gy * blockIdx.z);
  const int cpx = nwg >> 3;
  const int nid = (orig & 7) * cpx + (orig >> 3);
  const int bxi = nid % gx;
  const int byi = (nid / gx) % gy;
  const int bzi = nid / (gx * gy);
  const int m0 = byi * 256, n0 = bxi * 256;

  const u16* Ab = A + (size_t)bzi * Ab_str;
  const u16* Bb = B + (size_t)bzi * Bb_str;
  float* zb = z + (size_t)bzi * 8192;

  const int tid = threadIdx.x;
  const int l = tid & 63;
  const int w = tid >> 6;              // wave 0..7
  const int wm = w >> 2, wn = w & 3;   // 2(M) x 4(N)

  // ---- staging constants (write side; inverse-swizzled global source) ----
  const int rowS = tid >> 3;                                  // 0..63
  const int cS = ((tid & 7) << 4) ^ ((rowS & 7) << 4);        // src byte col
  const u16* srcA[4];
  const u16* srcB[4];
#pragma unroll
  for (int j = 0; j < 4; j++) {
    srcA[j] = Ab + (size_t)(m0 + rowS + j * 64) * Kstride + (cS >> 1);
    srcB[j] = Bb + (size_t)(n0 + rowS + j * 64) * Kstride + (cS >> 1);
  }

  // ---- read-side constants (swizzled ds_read addresses) ----
  const int fr = l & 15;                       // fragment row (within 16)
  const int X = (fr & 7) << 4;                 // swizzle mask (bytes)
  const int kb = (l >> 4) << 4;                // 0,16,32,48 byte col
  const int swz0 = ((kb ^ X)) >> 1;            // u16 units, k-slice 0
  const int swz1 = (((64 + kb) ^ X)) >> 1;     // k-slice 1
  const int aRow = (wm * 128 + fr) * 64;       // u16 index of row base
  const int bRow = (wn * 64 + fr) * 64;

  // ---- prologue: stage tile 0 into buf0 ----
#pragma unroll
  for (int j = 0; j < 4; j++) {
    gl_lds16(srcA[j], &lA[0][w * 512 + j * 4096]);
    gl_lds16(srcB[j], &lB[0][w * 512 + j * 4096]);
  }
  if (EPI == 2 && tid < 256) rz_lds[tid] = 1.f / zb[m0 + tid];
  __syncthreads();  // compiler drains vmcnt before barrier -> buf0 ready

  f32x4 acc[8][4] = {};

  for (int t = 0; t < nt; ++t) {
    const int cur = t & 1;
    if (t + 1 < nt) {  // prefetch next K-tile into other buffer
#pragma unroll
      for (int j = 0; j < 4; j++) {
        gl_lds16(srcA[j] + (t + 1) * 64, &lA[cur ^ 1][w * 512 + j * 4096]);
        gl_lds16(srcB[j] + (t + 1) * 64, &lB[cur ^ 1][w * 512 + j * 4096]);
      }
    }
    const u16* la = lA[cur];
    const u16* lb = lB[cur];
    bf16x8 bfrag[4][2];
#pragma unroll
    for (int n = 0; n < 4; n++) {
      bfrag[n][0] = *(const bf16x8*)&lb[bRow + n * 1024 + swz0];
      bfrag[n][1] = *(const bf16x8*)&lb[bRow + n * 1024 + swz1];
    }
#pragma unroll
    for (int mp = 0; mp < 4; mp++) {
      bf16x8 afr[2][2];
#pragma unroll
      for (int mi = 0; mi < 2; mi++) {
        const int m = mp * 2 + mi;
        afr[mi][0] = *(const bf16x8*)&la[aRow + m * 1024 + swz0];
        afr[mi][1] = *(const bf16x8*)&la[aRow + m * 1024 + swz1];
      }
      __builtin_amdgcn_s_setprio(1);
#pragma unroll
      for (int mi = 0; mi < 2; mi++)
#pragma unroll
        for (int n = 0; n < 4; n++) {
          acc[mp * 2 + mi][n] = __builtin_amdgcn_mfma_f32_16x16x32_bf16(
              afr[mi][0], bfrag[n][0], acc[mp * 2 + mi][n], 0, 0, 0);
          acc[mp * 2 + mi][n] = __builtin_amdgcn_mfma_f32_16x16x32_bf16(
              afr[mi][1], bfrag[n][1], acc[mp * 2 + mi][n], 0, 0, 0);
        }
      __builtin_amdgcn_s_setprio(0);
    }
    __syncthreads();  // staged tile t+1 complete + visible; buf[cur] reusable
  }

  // ---- epilogue ----
  const int rq = (l >> 4) * 4;  // C/D: col=lane&15, row=(lane>>4)*4+reg
#pragma unroll
  for (int m = 0; m < 8; m++) {
    const int lrow = wm * 128 + m * 16 + rq;   // local row in 256-tile
    const int grow = m0 + lrow;
    float rs[4] = {0.f, 0.f, 0.f, 0.f};
#pragma unroll
    for (int n = 0; n < 4; n++) {
      const int col = n0 + wn * 64 + n * 16 + fr;
#pragma unroll
      for (int r = 0; r < 4; r++) {
        const float v = acc[m][n][r];
        if (EPI == 0) {
          const float e = __expf(v);
          ((u16*)Cout)[(size_t)bzi * Cb_str + (size_t)(grow + r) * N + col] = f2bf(e);
          rs[r] += e;
        } else {
          ((float*)Cout)[(size_t)bzi * Cb_str + (size_t)(grow + r) * N + col] =
              v * rz_lds[lrow + r];
        }
      }
    }
    if (EPI == 0) {
#pragma unroll
      for (int s = 1; s < 16; s <<= 1)
#pragma unroll
        for (int r = 0; r < 4; r++) rs[r] += __shfl_xor(rs[r], s);
      if (fr == 0) {
#pragma unroll
        for (int r = 0; r < 4; r++) atomicAdd(&zb[grow + r], rs[r]);
      }
    }
  }
}

// B=8, L=2048, D=512, Y=8192
extern "C" void kernel_launch(void* const* d_in, const int* in_sizes, int n_in,
                              void* d_out, int out_size, void* d_ws, size_t ws_size,
                              hipStream_t stream) {
  const float* x = (const float*)d_in[0];   // [8][2048][512]
  const float* U = (const float*)d_in[1];   // [8192][512]
  if (n_in >= 2 && in_sizes[0] == 8192 * 512) {
    x = (const float*)d_in[1];
    U = (const float*)d_in[0];
  }
  float* out = (float*)d_out;               // [8][8192][512]
  char* ws = (char*)d_ws;

  // ws layout (bytes)
  u16* Ub = (u16*)ws;                       // 8 MiB
  u16* Xb = (u16*)(ws + 8388608);           // 16 MiB
  u16* XT = (u16*)(ws + 25165824);          // 16 MiB
  u16* P  = (u16*)(ws + 41943040);          // all-batch: 256 MiB
  const size_t need_all = 41943040ull + 268435456ull + 262144ull;

  cvt_bf16<<<4096, 256, 0, stream>>>(U, Ub, (8192 * 512) / 4);
  prep_x<<<dim3(16, 64, 8), 256, 0, stream>>>(x, Xb, XT);

  if (ws_size >= need_all) {
    float* z = (float*)(ws + 41943040 + 268435456);
    zero_f32<<<256, 256, 0, stream>>>(z, 8 * 8192);
    // P[b] = exp(U @ x_b^T), fused rowsum -> z[b]: M=8192, N=2048, K=512
    gemm256<0><<<dim3(8, 32, 8), 512, 0, stream>>>(
        Ub, Xb, P, z, 512, 8, 2048,
        0, (size_t)2048 * 512, (size_t)8192 * 2048, 8, 32);
    // out[b] = (P[b] @ XT_b^T) / z[b]: M=8192, N=512, K=2048
    gemm256<2><<<dim3(2, 32, 8), 512, 0, stream>>>(
        P, XT, out, z, 2048, 32, 512,
        (size_t)8192 * 2048, (size_t)512 * 2048, (size_t)8192 * 512, 2, 32);
  } else {
    // fallback: per-batch P (32 MiB)
    float* z = (float*)(ws + 41943040 + 33554432);
    zero_f32<<<256, 256, 0, stream>>>(z, 8 * 8192);
    for (int b = 0; b < 8; b++) {
      gemm256<0><<<dim3(8, 32, 1), 512, 0, stream>>>(
          Ub, Xb + (size_t)b * 2048 * 512, P, z + b * 8192, 512, 8, 2048,
          0, 0, 0, 8, 32);
      gemm256<2><<<dim3(2, 32, 1), 512, 0, stream>>>(
          P, XT + (size_t)b * 512 * 2048, out + (size_t)b * 8192 * 512,
          z + b * 8192, 2048, 32, 512, 0, 0, 0, 2, 32);
    }
  }
}

// Round 5
// 493.916 us; speedup vs baseline: 1.4994x; 1.0588x over previous
//
#include <hip/hip_runtime.h>

typedef unsigned short u16;
typedef unsigned int u32;
typedef __attribute__((ext_vector_type(8))) short bf16x8;
typedef __attribute__((ext_vector_type(4))) float f32x4;

__device__ __forceinline__ u16 f2bf(float f) {
  u32 u = __float_as_uint(f);
  u32 r = (u + 0x7FFFu + ((u >> 16) & 1u)) >> 16;  // RTNE
  return (u16)r;
}

__device__ __forceinline__ void gl_lds16(const u16* g, u16* l) {
  __builtin_amdgcn_global_load_lds(
      (const __attribute__((address_space(1))) u32*)g,
      (__attribute__((address_space(3))) u32*)l, 16, 0, 0);
}

#define BAR() __builtin_amdgcn_s_barrier()
#define LGKM0()                                        \
  do {                                                 \
    asm volatile("s_waitcnt lgkmcnt(0)" ::: "memory"); \
    __builtin_amdgcn_sched_barrier(0);                 \
  } while (0)
#define VMW(N)                                              \
  do {                                                      \
    asm volatile("s_waitcnt vmcnt(" #N ")" ::: "memory");   \
    __builtin_amdgcn_sched_barrier(0);                      \
  } while (0)

// ---------------- prep: U fp32 -> bf16 ----------------
__global__ __launch_bounds__(256) void cvt_bf16(const float* __restrict__ src,
                                                u16* __restrict__ dst, int n4) {
  int g = blockIdx.x * 256 + threadIdx.x;
  if (g < n4) {
    float4 v = ((const float4*)src)[g];
    ushort4 o;
    o.x = f2bf(v.x); o.y = f2bf(v.y); o.z = f2bf(v.z); o.w = f2bf(v.w);
    ((ushort4*)dst)[g] = o;
  }
}

// ---------------- prep: x fp32 -> Xb bf16 [b][l][d] and XT bf16 [b][d][l] ----------------
__global__ __launch_bounds__(256) void prep_x(const float* __restrict__ x,
                                              u16* __restrict__ Xb,
                                              u16* __restrict__ XT) {
  __shared__ u16 t[32][33];
  const int b = blockIdx.z;
  const int l0 = blockIdx.y * 32;
  const int d0 = blockIdx.x * 32;
  const int j = threadIdx.x & 31;
  const int t5 = threadIdx.x >> 5;
#pragma unroll
  for (int r = 0; r < 4; r++) {
    int i = r * 8 + t5;
    float v = x[((size_t)b * 2048 + l0 + i) * 512 + d0 + j];
    u16 h = f2bf(v);
    t[i][j] = h;
    Xb[((size_t)b * 2048 + l0 + i) * 512 + d0 + j] = h;
  }
  __syncthreads();
#pragma unroll
  for (int r = 0; r < 4; r++) {
    int i = r * 8 + t5;
    XT[((size_t)b * 512 + d0 + i) * 2048 + l0 + j] = t[j][i];
  }
}

__global__ __launch_bounds__(256) void zero_f32(float* __restrict__ p, int n) {
  int g = blockIdx.x * 256 + threadIdx.x;
  if (g < n) p[g] = 0.f;
}

// ---------------- 256x256-tile batched GEMM: C[b] = A[b] @ B[b]^T ----------------
// BK=64, 8 waves (2M x 4N), double-buffered swizzled LDS, 4-phase counted
// schedule per K-tile (T3+T4+T5): stages stay in flight across phases, one
// vmcnt(4) gate per tile, raw s_barrier, lgkmcnt(0)+sched_barrier fences.
// EPI=0: out = bf16(exp(acc)) -> u16* stride N; fused rowsum atomicAdd into z
// EPI=2: out = acc / z[row]   -> float* stride N
template <int EPI>
__global__ __launch_bounds__(512, 2)
void gemm256(const u16* __restrict__ A, const u16* __restrict__ B,
             void* __restrict__ Cout, float* __restrict__ z,
             int Kstride, int nt, int N,
             size_t Ab_str, size_t Bb_str, size_t Cb_str, int gx, int gy) {
  __shared__ u16 lA[2][16384];   // [buf][256 rows][64 k] swizzled, 32 KiB each
  __shared__ u16 lB[2][16384];
  __shared__ float rz_lds[256];

  // flatten + XCD-bijective swizzle (nwg % 8 == 0 in all launches)
  const int nwg = gx * gy * gridDim.z;
  const int orig = blockIdx.x + gx * (blockIdx.y + gy * blockIdx.z);
  const int cpx = nwg >> 3;
  const int nid = (orig & 7) * cpx + (orig >> 3);
  const int bxi = nid % gx;
  const int byi = (nid / gx) % gy;
  const int bzi = nid / (gx * gy);
  const int m0 = byi * 256, n0 = bxi * 256;

  const u16* Ab = A + (size_t)bzi * Ab_str;
  const u16* Bb = B + (size_t)bzi * Bb_str;
  float* zb = z + (size_t)bzi * 8192;

  const int tid = threadIdx.x;
  const int l = tid & 63;
  const int w = tid >> 6;              // wave 0..7
  const int wm = w >> 2, wn = w & 3;   // 2(M) x 4(N)

  // ---- staging constants (write side; inverse-swizzled global source) ----
  const int rowS = tid >> 3;                                  // 0..63
  const int cS = ((tid & 7) << 4) ^ ((rowS & 7) << 4);        // src byte col
  const u16* srcA[4];
  const u16* srcB[4];
#pragma unroll
  for (int j = 0; j < 4; j++) {
    srcA[j] = Ab + (size_t)(m0 + rowS + j * 64) * Kstride + (cS >> 1);
    srcB[j] = Bb + (size_t)(n0 + rowS + j * 64) * Kstride + (cS >> 1);
  }

  // ---- read-side constants (swizzled ds_read addresses) ----
  const int fr = l & 15;                       // fragment row (within 16)
  const int X = (fr & 7) << 4;                 // swizzle mask (bytes)
  const int kb = (l >> 4) << 4;                // 0,16,32,48 byte col
  const int swz0 = ((kb ^ X)) >> 1;            // u16 units, k-slice 0
  const int swz1 = (((64 + kb) ^ X)) >> 1;     // k-slice 1
  const int aRow = (wm * 128 + fr) * 64;       // u16 index of row base
  const int bRow = (wn * 64 + fr) * 64;

  // ---- prologue: stage tile0 (A+B), tile1 (A only); B of tile1 in-loop ----
#pragma unroll
  for (int j = 0; j < 4; j++) gl_lds16(srcA[j], &lA[0][w * 512 + j * 4096]);
#pragma unroll
  for (int j = 0; j < 4; j++) gl_lds16(srcB[j], &lB[0][w * 512 + j * 4096]);
  if (nt > 1) {
#pragma unroll
    for (int j = 0; j < 4; j++)
      gl_lds16(srcA[j] + 64, &lA[1][w * 512 + j * 4096]);
  }
  if (EPI == 2 && tid < 256) rz_lds[tid] = 1.f / zb[m0 + tid];
  if (nt > 1) { VMW(4); } else { VMW(0); }
  BAR();

  f32x4 acc[8][4] = {};

  for (int t = 0; t < nt; ++t) {
    const int cur = t & 1;
    const u16* la = lA[cur];
    const u16* lb = lB[cur];
    u16* stB = lB[cur ^ 1];        // B halves of tile t+1
    u16* stA = lA[cur];            // A halves of tile t+2 (same parity buf)
    const bool st1 = (t + 1 < nt);
    const bool st2 = (t + 2 < nt);
    bf16x8 a0[8], a1[8], b0[4], b1[4];

    // ---------- phase 1: read ks0 frags; stage B-half0(t+1); MFMA m0-3 ks0 ----------
#pragma unroll
    for (int m = 0; m < 8; m++) a0[m] = *(const bf16x8*)&la[aRow + m * 1024 + swz0];
#pragma unroll
    for (int n = 0; n < 4; n++) b0[n] = *(const bf16x8*)&lb[bRow + n * 1024 + swz0];
    if (st1) {
      gl_lds16(srcB[0] + (t + 1) * 64, &stB[w * 512 + 0 * 4096]);
      gl_lds16(srcB[1] + (t + 1) * 64, &stB[w * 512 + 1 * 4096]);
    }
    BAR();
    LGKM0();
    __builtin_amdgcn_s_setprio(1);
#pragma unroll
    for (int m = 0; m < 4; m++)
#pragma unroll
      for (int n = 0; n < 4; n++)
        acc[m][n] = __builtin_amdgcn_mfma_f32_16x16x32_bf16(a0[m], b0[n], acc[m][n], 0, 0, 0);
    __builtin_amdgcn_s_setprio(0);
    BAR();

    // ---------- phase 2: read a1[0..3],b1; stage B-half1(t+1); MFMA m4-7 ks0 ----------
#pragma unroll
    for (int m = 0; m < 4; m++) a1[m] = *(const bf16x8*)&la[aRow + m * 1024 + swz1];
#pragma unroll
    for (int n = 0; n < 4; n++) b1[n] = *(const bf16x8*)&lb[bRow + n * 1024 + swz1];
    if (st1) {
      gl_lds16(srcB[2] + (t + 1) * 64, &stB[w * 512 + 2 * 4096]);
      gl_lds16(srcB[3] + (t + 1) * 64, &stB[w * 512 + 3 * 4096]);
    }
    BAR();
    LGKM0();
    __builtin_amdgcn_s_setprio(1);
#pragma unroll
    for (int m = 4; m < 8; m++)
#pragma unroll
      for (int n = 0; n < 4; n++)
        acc[m][n] = __builtin_amdgcn_mfma_f32_16x16x32_bf16(a0[m], b0[n], acc[m][n], 0, 0, 0);
    __builtin_amdgcn_s_setprio(0);
    BAR();

    // ---------- phase 3: read a1[4..7]; MFMA m0-3 ks1; drain own ds_reads ----------
#pragma unroll
    for (int m = 4; m < 8; m++) a1[m] = *(const bf16x8*)&la[aRow + m * 1024 + swz1];
    __builtin_amdgcn_s_setprio(1);
#pragma unroll
    for (int m = 0; m < 4; m++)
#pragma unroll
      for (int n = 0; n < 4; n++)
        acc[m][n] = __builtin_amdgcn_mfma_f32_16x16x32_bf16(a1[m], b1[n], acc[m][n], 0, 0, 0);
    __builtin_amdgcn_s_setprio(0);
    LGKM0();   // all reads of buf[cur] complete before any wave passes this barrier
    BAR();

    // ---------- phase 4: stage A-half0+1(t+2) into freed buf; MFMA m4-7 ks1; gate ----------
    if (st2) {
      gl_lds16(srcA[0] + (t + 2) * 64, &stA[w * 512 + 0 * 4096]);
      gl_lds16(srcA[1] + (t + 2) * 64, &stA[w * 512 + 1 * 4096]);
      gl_lds16(srcA[2] + (t + 2) * 64, &stA[w * 512 + 2 * 4096]);
      gl_lds16(srcA[3] + (t + 2) * 64, &stA[w * 512 + 3 * 4096]);
    }
    __builtin_amdgcn_s_setprio(1);
#pragma unroll
    for (int m = 4; m < 8; m++)
#pragma unroll
      for (int n = 0; n < 4; n++)
        acc[m][n] = __builtin_amdgcn_mfma_f32_16x16x32_bf16(a1[m], b1[n], acc[m][n], 0, 0, 0);
    __builtin_amdgcn_s_setprio(0);
    if (st1) {
      if (st2) { VMW(4); } else { VMW(0); }  // tile t+1 fully resident past here
    }
    BAR();
  }

  // ---- epilogue ----
  const int rq = (l >> 4) * 4;  // C/D: col=lane&15, row=(lane>>4)*4+reg
#pragma unroll
  for (int m = 0; m < 8; m++) {
    const int lrow = wm * 128 + m * 16 + rq;   // local row in 256-tile
    const int grow = m0 + lrow;
    float rs[4] = {0.f, 0.f, 0.f, 0.f};
#pragma unroll
    for (int n = 0; n < 4; n++) {
      const int col = n0 + wn * 64 + n * 16 + fr;
#pragma unroll
      for (int r = 0; r < 4; r++) {
        const float v = acc[m][n][r];
        if (EPI == 0) {
          const float e = __expf(v);
          ((u16*)Cout)[(size_t)bzi * Cb_str + (size_t)(grow + r) * N + col] = f2bf(e);
          rs[r] += e;
        } else {
          ((float*)Cout)[(size_t)bzi * Cb_str + (size_t)(grow + r) * N + col] =
              v * rz_lds[lrow + r];
        }
      }
    }
    if (EPI == 0) {
#pragma unroll
      for (int s = 1; s < 16; s <<= 1)
#pragma unroll
        for (int r = 0; r < 4; r++) rs[r] += __shfl_xor(rs[r], s);
      if (fr == 0) {
#pragma unroll
        for (int r = 0; r < 4; r++) atomicAdd(&zb[grow + r], rs[r]);
      }
    }
  }
}

// B=8, L=2048, D=512, Y=8192
extern "C" void kernel_launch(void* const* d_in, const int* in_sizes, int n_in,
                              void* d_out, int out_size, void* d_ws, size_t ws_size,
                              hipStream_t stream) {
  const float* x = (const float*)d_in[0];   // [8][2048][512]
  const float* U = (const float*)d_in[1];   // [8192][512]
  if (n_in >= 2 && in_sizes[0] == 8192 * 512) {
    x = (const float*)d_in[1];
    U = (const float*)d_in[0];
  }
  float* out = (float*)d_out;               // [8][8192][512]
  char* ws = (char*)d_ws;

  // ws layout (bytes)
  u16* Ub = (u16*)ws;                       // 8 MiB
  u16* Xb = (u16*)(ws + 8388608);           // 16 MiB
  u16* XT = (u16*)(ws + 25165824);          // 16 MiB
  u16* P  = (u16*)(ws + 41943040);          // all-batch: 256 MiB
  const size_t need_all = 41943040ull + 268435456ull + 262144ull;

  cvt_bf16<<<4096, 256, 0, stream>>>(U, Ub, (8192 * 512) / 4);
  prep_x<<<dim3(16, 64, 8), 256, 0, stream>>>(x, Xb, XT);

  if (ws_size >= need_all) {
    float* z = (float*)(ws + 41943040 + 268435456);
    zero_f32<<<256, 256, 0, stream>>>(z, 8 * 8192);
    // P[b] = exp(U @ x_b^T), fused rowsum -> z[b]: M=8192, N=2048, K=512
    gemm256<0><<<dim3(8, 32, 8), 512, 0, stream>>>(
        Ub, Xb, P, z, 512, 8, 2048,
        0, (size_t)2048 * 512, (size_t)8192 * 2048, 8, 32);
    // out[b] = (P[b] @ XT_b^T) / z[b]: M=8192, N=512, K=2048
    gemm256<2><<<dim3(2, 32, 8), 512, 0, stream>>>(
        P, XT, out, z, 2048, 32, 512,
        (size_t)8192 * 2048, (size_t)512 * 2048, (size_t)8192 * 512, 2, 32);
  } else {
    // fallback: per-batch P (32 MiB)
    float* z = (float*)(ws + 41943040 + 33554432);
    zero_f32<<<256, 256, 0, stream>>>(z, 8 * 8192);
    for (int b = 0; b < 8; b++) {
      gemm256<0><<<dim3(8, 32, 1), 512, 0, stream>>>(
          Ub, Xb + (size_t)b * 2048 * 512, P, z + b * 8192, 512, 8, 2048,
          0, 0, 0, 8, 32);
      gemm256<2><<<dim3(2, 32, 1), 512, 0, stream>>>(
          P, XT + (size_t)b * 512 * 2048, out + (size_t)b * 8192 * 512,
          z + b * 8192, 2048, 32, 512, 0, 0, 0, 2, 32);
    }
  }
}

// Round 6
// 455.056 us; speedup vs baseline: 1.6274x; 1.0854x over previous
//
#include <hip/hip_runtime.h>

typedef unsigned short u16;
typedef unsigned int u32;
typedef __attribute__((ext_vector_type(8))) short bf16x8;
typedef __attribute__((ext_vector_type(4))) float f32x4;

__device__ __forceinline__ u16 f2bf(float f) {
  u32 u = __float_as_uint(f);
  u32 r = (u + 0x7FFFu + ((u >> 16) & 1u)) >> 16;  // RTNE
  return (u16)r;
}

__device__ __forceinline__ void gl_lds16(const u16* g, u16* l) {
  __builtin_amdgcn_global_load_lds(
      (const __attribute__((address_space(1))) u32*)g,
      (__attribute__((address_space(3))) u32*)l, 16, 0, 0);
}

// ---------------- prep: U fp32 -> bf16 ----------------
__global__ __launch_bounds__(256) void cvt_bf16(const float* __restrict__ src,
                                                u16* __restrict__ dst, int n4) {
  int g = blockIdx.x * 256 + threadIdx.x;
  if (g < n4) {
    float4 v = ((const float4*)src)[g];
    ushort4 o;
    o.x = f2bf(v.x); o.y = f2bf(v.y); o.z = f2bf(v.z); o.w = f2bf(v.w);
    ((ushort4*)dst)[g] = o;
  }
}

// ---------------- prep: x fp32 -> Xb bf16 [b][l][d] and XT bf16 [b][d][l] ----------------
__global__ __launch_bounds__(256) void prep_x(const float* __restrict__ x,
                                              u16* __restrict__ Xb,
                                              u16* __restrict__ XT) {
  __shared__ u16 t[32][33];
  const int b = blockIdx.z;
  const int l0 = blockIdx.y * 32;
  const int d0 = blockIdx.x * 32;
  const int j = threadIdx.x & 31;
  const int t5 = threadIdx.x >> 5;
#pragma unroll
  for (int r = 0; r < 4; r++) {
    int i = r * 8 + t5;
    float v = x[((size_t)b * 2048 + l0 + i) * 512 + d0 + j];
    u16 h = f2bf(v);
    t[i][j] = h;
    Xb[((size_t)b * 2048 + l0 + i) * 512 + d0 + j] = h;
  }
  __syncthreads();
#pragma unroll
  for (int r = 0; r < 4; r++) {
    int i = r * 8 + t5;
    XT[((size_t)b * 512 + d0 + i) * 2048 + l0 + j] = t[j][i];
  }
}

__global__ __launch_bounds__(256) void zero_f32(float* __restrict__ p, int n) {
  int g = blockIdx.x * 256 + threadIdx.x;
  if (g < n) p[g] = 0.f;
}

// ---------------- 128x128-tile batched GEMM: C[b] = A[b] @ B[b]^T ----------------
// m97-regime: BK=64, 4 waves (2x2, 64x64/wave), single-buffered 32 KiB LDS,
// swizzled rows (byte ^= (row&7)<<4), simple 2-barrier loop, 3 blocks/CU.
// Cross-block TLP (12 waves/CU) hides staging drains and epilogues.
// EPI=0: out = bf16(exp(acc)) -> u16* stride N; fused rowsum atomicAdd into z
// EPI=2: out = acc / z[row]   -> float* stride N
template <int EPI>
__global__ __launch_bounds__(256, 3)
void gemm128(const u16* __restrict__ A, const u16* __restrict__ B,
             void* __restrict__ Cout, float* __restrict__ z,
             int Kstride, int nt, int N,
             size_t Ab_str, size_t Bb_str, size_t Cb_str, int gx, int gy) {
  __shared__ u16 lA[8192];   // [128 rows][64 k] swizzled, 16 KiB
  __shared__ u16 lB[8192];
  __shared__ float rz_lds[128];

  // flatten + XCD-bijective swizzle (nwg % 8 == 0 in all launches)
  const int nwg = gx * gy * gridDim.z;
  const int orig = blockIdx.x + gx * (blockIdx.y + gy * blockIdx.z);
  const int cpx = nwg >> 3;
  const int nid = (orig & 7) * cpx + (orig >> 3);
  const int bxi = nid % gx;
  const int byi = (nid / gx) % gy;
  const int bzi = nid / (gx * gy);
  const int m0 = byi * 128, n0 = bxi * 128;

  const u16* Ab = A + (size_t)bzi * Ab_str;
  const u16* Bb = B + (size_t)bzi * Bb_str;
  float* zb = z + (size_t)bzi * 8192;

  const int tid = threadIdx.x;
  const int l = tid & 63;
  const int w = tid >> 6;              // wave 0..3
  const int wy = w >> 1, wx = w & 1;   // 2x2 wave grid, 64x64 per wave

  // ---- staging constants (write side; inverse-swizzled global source) ----
  const int rowS = tid >> 3;                                  // 0..31
  const int cS = ((tid & 7) << 4) ^ ((rowS & 7) << 4);        // src byte col
  const u16* srcA[4];
  const u16* srcB[4];
#pragma unroll
  for (int j = 0; j < 4; j++) {
    srcA[j] = Ab + (size_t)(m0 + rowS + j * 32) * Kstride + (cS >> 1);
    srcB[j] = Bb + (size_t)(n0 + rowS + j * 32) * Kstride + (cS >> 1);
  }

  // ---- read-side constants (swizzled ds_read addresses) ----
  const int fr = l & 15;                       // fragment row (within 16)
  const int X = (fr & 7) << 4;                 // swizzle mask (bytes)
  const int kb = (l >> 4) << 4;                // 0,16,32,48 byte col
  const int swz0 = (kb ^ X) >> 1;              // u16 units, k-slice 0
  const int swz1 = ((64 + kb) ^ X) >> 1;       // k-slice 1
  const int aRow = (wy * 64 + fr) * 64;        // u16 index of row base (m=0)
  const int bRow = (wx * 64 + fr) * 64;

  if (EPI == 2 && tid < 128) rz_lds[tid] = 1.f / zb[m0 + tid];

  f32x4 acc[4][4] = {};

  for (int t = 0; t < nt; ++t) {
#pragma unroll
    for (int j = 0; j < 4; j++) {
      gl_lds16(srcA[j] + t * 64, &lA[tid * 8 + j * 2048]);
      gl_lds16(srcB[j] + t * 64, &lB[tid * 8 + j * 2048]);
    }
    __syncthreads();   // drains vmcnt -> tile resident
#pragma unroll
    for (int ks = 0; ks < 2; ks++) {
      const int swz = ks ? swz1 : swz0;
      bf16x8 bfr[4], afr[4];
#pragma unroll
      for (int n = 0; n < 4; n++) bfr[n] = *(const bf16x8*)&lB[bRow + n * 1024 + swz];
#pragma unroll
      for (int m = 0; m < 4; m++) afr[m] = *(const bf16x8*)&lA[aRow + m * 1024 + swz];
#pragma unroll
      for (int m = 0; m < 4; m++)
#pragma unroll
        for (int n = 0; n < 4; n++)
          acc[m][n] = __builtin_amdgcn_mfma_f32_16x16x32_bf16(
              afr[m], bfr[n], acc[m][n], 0, 0, 0);
    }
    __syncthreads();   // reads done before next stage overwrites
  }

  // ---- epilogue ----
  const int rq = (l >> 4) * 4;  // C/D: col=lane&15, row=(lane>>4)*4+reg
#pragma unroll
  for (int m = 0; m < 4; m++) {
    const int lrow = wy * 64 + m * 16 + rq;    // local row in 128-tile
    const int grow = m0 + lrow;
    float rs[4] = {0.f, 0.f, 0.f, 0.f};
#pragma unroll
    for (int n = 0; n < 4; n++) {
      const int col = n0 + wx * 64 + n * 16 + fr;
#pragma unroll
      for (int r = 0; r < 4; r++) {
        const float v = acc[m][n][r];
        if (EPI == 0) {
          const float e = __expf(v);
          ((u16*)Cout)[(size_t)bzi * Cb_str + (size_t)(grow + r) * N + col] = f2bf(e);
          rs[r] += e;
        } else {
          ((float*)Cout)[(size_t)bzi * Cb_str + (size_t)(grow + r) * N + col] =
              v * rz_lds[lrow + r];
        }
      }
    }
    if (EPI == 0) {
#pragma unroll
      for (int s = 1; s < 16; s <<= 1)
#pragma unroll
        for (int r = 0; r < 4; r++) rs[r] += __shfl_xor(rs[r], s);
      if (fr == 0) {
#pragma unroll
        for (int r = 0; r < 4; r++) atomicAdd(&zb[grow + r], rs[r]);
      }
    }
  }
}

// B=8, L=2048, D=512, Y=8192
extern "C" void kernel_launch(void* const* d_in, const int* in_sizes, int n_in,
                              void* d_out, int out_size, void* d_ws, size_t ws_size,
                              hipStream_t stream) {
  const float* x = (const float*)d_in[0];   // [8][2048][512]
  const float* U = (const float*)d_in[1];   // [8192][512]
  if (n_in >= 2 && in_sizes[0] == 8192 * 512) {
    x = (const float*)d_in[1];
    U = (const float*)d_in[0];
  }
  float* out = (float*)d_out;               // [8][8192][512]
  char* ws = (char*)d_ws;

  // ws layout (bytes)
  u16* Ub = (u16*)ws;                       // 8 MiB
  u16* Xb = (u16*)(ws + 8388608);           // 16 MiB
  u16* XT = (u16*)(ws + 25165824);          // 16 MiB
  u16* P  = (u16*)(ws + 41943040);          // all-batch: 256 MiB
  const size_t need_all = 41943040ull + 268435456ull + 262144ull;

  cvt_bf16<<<4096, 256, 0, stream>>>(U, Ub, (8192 * 512) / 4);
  prep_x<<<dim3(16, 64, 8), 256, 0, stream>>>(x, Xb, XT);

  if (ws_size >= need_all) {
    float* z = (float*)(ws + 41943040 + 268435456);
    zero_f32<<<256, 256, 0, stream>>>(z, 8 * 8192);
    // P[b] = exp(U @ x_b^T), fused rowsum -> z[b]: M=8192, N=2048, K=512
    gemm128<0><<<dim3(16, 64, 8), 256, 0, stream>>>(
        Ub, Xb, P, z, 512, 8, 2048,
        0, (size_t)2048 * 512, (size_t)8192 * 2048, 16, 64);
    // out[b] = (P[b] @ XT_b^T) / z[b]: M=8192, N=512, K=2048
    gemm128<2><<<dim3(4, 64, 8), 256, 0, stream>>>(
        P, XT, out, z, 2048, 32, 512,
        (size_t)8192 * 2048, (size_t)512 * 2048, (size_t)8192 * 512, 4, 64);
  } else {
    // fallback: per-batch P (32 MiB)
    float* z = (float*)(ws + 41943040 + 33554432);
    zero_f32<<<256, 256, 0, stream>>>(z, 8 * 8192);
    for (int b = 0; b < 8; b++) {
      gemm128<0><<<dim3(16, 64, 1), 256, 0, stream>>>(
          Ub, Xb + (size_t)b * 2048 * 512, P, z + b * 8192, 512, 8, 2048,
          0, 0, 0, 16, 64);
      gemm128<2><<<dim3(4, 64, 1), 256, 0, stream>>>(
          P, XT + (size_t)b * 512 * 2048, out + (size_t)b * 8192 * 512,
          z + b * 8192, 2048, 32, 512, 0, 0, 0, 4, 64);
    }
  }
}